// Round 7
// baseline (287.332 us; speedup 1.0000x reference)
//
#include <hip/hip_runtime.h>

#define CC 128
#define HH 80
#define WW 256
#define NSL 320                 // 4*80 slices
#define TRI2_TOT 36864          // quad-uniform staggered triangle, floats (144 KB)
#define DISP_OFF 0
#define CONF_OFF 81920
#define OCC_OFF  163840
#define CV_OFF   245760
#define CVD_OFF  21217280
#define NU_C (1.0f/512.0f)
#define MU_C (1.0f/512.0f)
#define ST_N 163840             // 8*80*256 pixels (mean at [0], rstd at [ST_N])
#define LDSW 40                 // ushorts per LDS row (32 data + 8 pad = 80 B)

typedef _Float16 f16;
typedef f16 f16x8 __attribute__((ext_vector_type(8)));
typedef float f32x4 __attribute__((ext_vector_type(4)));

// Quad m (rows 4m..4m+3) all have padded length ell(m) = 4 + 32*((m+7)>>3).
// Row start S(i) = Q(m) + (i&3)*ell(m), Q(m) = 16m + 128*G(m).
__device__ __forceinline__ int ell_of(int m) { return 4 + (((m + 7) >> 3) << 5); }
__device__ __forceinline__ int S_of(int i) {
  int m = i >> 2;
  int q = (m + 7) >> 3, r = (m + 7) & 7;
  int Q = 16*m + ((q*(q-1)) << 9) + ((r*q) << 7);
  return Q + (i & 3) * ell_of(m);
}

// ---------------- LN stats: one pass over feature, 1.3 MB out ----------------
__global__ __launch_bounds__(256)
void ln_stats_kernel(const float* __restrict__ feat, float* __restrict__ stats) {
  __shared__ __align__(16) float4 psum[8][32];
  __shared__ __align__(16) float4 psq[8][32];
  const int t = threadIdx.x;
  const int id = blockIdx.x;              // 0..1279 = bh*2 + wx
  const int wx = id & 1, bh = id >> 1;
  const int bb = bh / HH, h = bh % HH;
  const int tw = t & 31, tc = t >> 5;
  const float* p = feat + ((size_t)(bb*CC + tc*16)*HH + h)*WW + wx*128 + tw*4;
  float4 s4  = make_float4(0.f, 0.f, 0.f, 0.f);
  float4 s24 = make_float4(0.f, 0.f, 0.f, 0.f);
  #pragma unroll
  for (int cc = 0; cc < 16; ++cc) {
    float4 v = *(const float4*)(p + (size_t)cc*HH*WW);
    s4.x += v.x; s4.y += v.y; s4.z += v.z; s4.w += v.w;
    s24.x = fmaf(v.x, v.x, s24.x); s24.y = fmaf(v.y, v.y, s24.y);
    s24.z = fmaf(v.z, v.z, s24.z); s24.w = fmaf(v.w, v.w, s24.w);
  }
  psum[tc][tw] = s4; psq[tc][tw] = s24;
  __syncthreads();
  if (t < 32) {
    float4 S  = psum[0][t];
    float4 S2 = psq[0][t];
    #pragma unroll
    for (int k = 1; k < 8; ++k) {
      float4 a = psum[k][t], b = psq[k][t];
      S.x += a.x; S.y += a.y; S.z += a.z; S.w += a.w;
      S2.x += b.x; S2.y += b.y; S2.z += b.z; S2.w += b.w;
    }
    float4 mu = make_float4(S.x*(1.f/CC), S.y*(1.f/CC), S.z*(1.f/CC), S.w*(1.f/CC));
    float4 rs;
    rs.x = rsqrtf(fmaf(-mu.x, mu.x, S2.x*(1.f/CC)) + 1e-5f);
    rs.y = rsqrtf(fmaf(-mu.y, mu.y, S2.y*(1.f/CC)) + 1e-5f);
    rs.z = rsqrtf(fmaf(-mu.z, mu.z, S2.z*(1.f/CC)) + 1e-5f);
    rs.w = rsqrtf(fmaf(-mu.w, mu.w, S2.w*(1.f/CC)) + 1e-5f);
    *(float4*)&stats[(size_t)bh*WW + wx*128 + 4*t]        = mu;
    *(float4*)&stats[ST_N + (size_t)bh*WW + wx*128 + 4*t] = rs;
  }
}

// ------------- fused cost-volume GEMM (cv + cvd), MFMA fp16-split ------------
// (validated R6: absmax 3.0, cv_fused < 99 us)
__global__ __launch_bounds__(256, 3)
void cv_fused_kernel(const float* __restrict__ feat, const float* __restrict__ stats,
                     const float* __restrict__ lnw, const float* __restrict__ lnb,
                     float* __restrict__ cv_out, float* __restrict__ cvd_out) {
  extern __shared__ unsigned short smu[];       // 20480 ushorts = 40960 B
  unsigned short* Ah = smu;
  unsigned short* Al = smu + 5120;
  unsigned short* Bh = smu + 10240;
  unsigned short* Bl = smu + 15360;
  __shared__ __align__(16) float rmean[256];
  __shared__ __align__(16) float rrstd[256];
  __shared__ float lwS[128], lbS[128];
  const int t = threadIdx.x;
  const int P = blockIdx.x;
  if (t < 128) { lwS[t] = lnw[t]; lbS[t] = lnb[t]; }
  const int l = t & 63, w = t >> 6;             // lane, wave
  const int wm = w >> 1, wn = w & 1;            // wave tile (64x64)
  const int fr = l & 15, fg = l >> 4;           // frag row, k-group
  const int row = t & 127, khalf = t >> 7;      // staging coords

  const bool iscv = (P < 4*NSL);
  int zz = 0, i0 = 0, j0 = 0, id = 0, ws = 1;
  size_t baseA, baseB;
  if (iscv) {
    const int x = P & 7, m = P >> 3;
    const int q = m & 3, zhi = m >> 2;
    zz = zhi*8 + x;                             // 0..319
    i0 = (q >> 1) * 128; j0 = (q & 1) * 128;
    const int b = zz / HH, h = zz % HH;
    baseA = ((size_t)b*CC*HH + (size_t)h)*WW + i0;
    baseB = ((size_t)(b+4)*CC*HH + (size_t)h)*WW + j0;
    const int isA = (t < 128);
    const int rr_ = isA ? (i0 + t) : (j0 + (t - 128));
    const int bb  = isA ? b : (b + 4);
    const size_t si = ((size_t)bb*HH + h)*WW + rr_;
    rmean[t] = stats[si];
    rrstd[t] = stats[ST_N + si];
  } else {
    id = P - 4*NSL;                             // 0..159
    const int b = id / 40, hd = id % 40, h = 2*hd;
    ws = 2;
    baseA = ((size_t)b*CC*HH + (size_t)h)*WW;
    baseB = ((size_t)(b+4)*CC*HH + (size_t)h)*WW;
    const int isA = (t < 128);
    const int rowd = isA ? t : (t - 128);
    const int bb = isA ? b : (b + 4);
    const size_t si = ((size_t)bb*HH + h)*WW + 2*rowd;
    rmean[t] = stats[si];
    rrstd[t] = stats[ST_N + si];
  }

  f32x4 acc[4][4];
  #pragma unroll
  for (int mi = 0; mi < 4; ++mi)
    #pragma unroll
    for (int ni = 0; ni < 4; ++ni)
      acc[mi][ni] = (f32x4){0.f, 0.f, 0.f, 0.f};

  float qa[16], qb[16];
  auto loadC = [&](int kc) {
    const size_t co = (size_t)(kc*32 + khalf*16)*HH*WW + (size_t)(row*ws);
    #pragma unroll
    for (int e = 0; e < 16; ++e) {
      qa[e] = feat[baseA + co + (size_t)e*HH*WW];
      qb[e] = feat[baseB + co + (size_t)e*HH*WW];
    }
  };
  auto storeC = [&](int kc) {
    const float rmA = rmean[row],     rrA = rrstd[row];
    const float rmB = rmean[128+row], rrB = rrstd[128+row];
    f16x8 vah[2], val[2], vbh[2], vbl[2];
    #pragma unroll
    for (int e = 0; e < 16; ++e) {
      const int ch = kc*32 + khalf*16 + e;
      const float lw = lwS[ch], lb = lbS[ch];
      float va = (qa[e] - rmA) * rrA * lw + lb;
      f16 ha = (f16)va;
      vah[e >> 3][e & 7] = ha;
      val[e >> 3][e & 7] = (f16)(va - (float)ha);
      float vb = (qb[e] - rmB) * rrB * lw + lb;
      f16 hb = (f16)vb;
      vbh[e >> 3][e & 7] = hb;
      vbl[e >> 3][e & 7] = (f16)(vb - (float)hb);
    }
    const int off = row*LDSW + khalf*16;
    *(f16x8*)&Ah[off] = vah[0]; *(f16x8*)&Ah[off + 8] = vah[1];
    *(f16x8*)&Al[off] = val[0]; *(f16x8*)&Al[off + 8] = val[1];
    *(f16x8*)&Bh[off] = vbh[0]; *(f16x8*)&Bh[off + 8] = vbh[1];
    *(f16x8*)&Bl[off] = vbl[0]; *(f16x8*)&Bl[off + 8] = vbl[1];
  };
  auto compute = [&]() {
    f16x8 a_h[4], a_l[4];
    #pragma unroll
    for (int mi = 0; mi < 4; ++mi) {
      const int r0 = (wm*64 + mi*16 + fr)*LDSW + fg*8;
      a_h[mi] = *(const f16x8*)&Ah[r0];
      a_l[mi] = *(const f16x8*)&Al[r0];
    }
    #pragma unroll
    for (int ni = 0; ni < 4; ++ni) {
      const int c0 = (wn*64 + ni*16 + fr)*LDSW + fg*8;
      f16x8 b_h = *(const f16x8*)&Bh[c0];
      f16x8 b_l = *(const f16x8*)&Bl[c0];
      #pragma unroll
      for (int mi = 0; mi < 4; ++mi) {
        acc[mi][ni] = __builtin_amdgcn_mfma_f32_16x16x32_f16(a_h[mi], b_h, acc[mi][ni], 0, 0, 0);
        acc[mi][ni] = __builtin_amdgcn_mfma_f32_16x16x32_f16(a_h[mi], b_l, acc[mi][ni], 0, 0, 0);
        acc[mi][ni] = __builtin_amdgcn_mfma_f32_16x16x32_f16(a_l[mi], b_h, acc[mi][ni], 0, 0, 0);
      }
    }
  };

  loadC(0);
  __syncthreads();                 // rmean/lwS visible
  storeC(0);
  for (int kc = 0; kc < 4; ++kc) {
    __syncthreads();               // LDS tile ready
    if (kc < 3) loadC(kc + 1);     // prefetch next chunk under compute
    compute();
    __syncthreads();               // all reads done before overwrite
    if (kc < 3) storeC(kc + 1);
  }

  // ---- epilogue: C/D layout row=(l>>4)*4+reg, col=l&15 ----
  if (iscv) {
    #pragma unroll
    for (int mi = 0; mi < 4; ++mi)
      #pragma unroll
      for (int ni = 0; ni < 4; ++ni) {
        f32x4 v = acc[mi][ni];
        const int orow = i0 + wm*64 + mi*16 + fg*4;
        const int ocol = j0 + wn*64 + ni*16 + fr;
        size_t ob = ((size_t)zz*256 + orow)*256 + ocol;
        cv_out[ob]       = v[0];
        cv_out[ob + 256] = v[1];
        cv_out[ob + 512] = v[2];
        cv_out[ob + 768] = v[3];
      }
  } else {
    #pragma unroll
    for (int mi = 0; mi < 4; ++mi)
      #pragma unroll
      for (int ni = 0; ni < 4; ++ni) {
        f32x4 v = acc[mi][ni];
        const int orow = wm*64 + mi*16 + fg*4;
        const int ocol = wn*64 + ni*16 + fr;
        size_t ob = ((size_t)id*128 + orow)*128 + ocol;
        cvd_out[ob]       = v[0];
        cvd_out[ob + 128] = v[1];
        cvd_out[ob + 256] = v[2];
        cvd_out[ob + 384] = v[3];
      }
  }
}

// ---------------- Sinkhorn: balanced 9-quad register stripes -----------------
// R7: 16-wave colsum (rows i ≡ w mod 16; was 8 waves + 8 idle) with two-stage
// buf merge; scalar (readfirstlane) row addressing so S_of runs on SALU;
// unroll-4 row chains. S_eu reduce moved into phase D (same values, bitwise
// identical order); redbufU init = 64 per group (eu=1 at it=0).
__global__ __launch_bounds__(1024)
__attribute__((amdgpu_waves_per_eu(4, 4)))
void sink_kernel(const float* __restrict__ cvg, float* __restrict__ out) {
  extern __shared__ float pE[];                 // TRI2_TOT floats
  __shared__ __align__(16) float eu[260];
  __shared__ __align__(16) float ev[260];
  __shared__ __align__(16) float buf[8][256];
  __shared__ float vbS[256];
  __shared__ float redbufU[4], redbufV[4], redbufM[16];
  __shared__ float Msh;
  const int t = threadIdx.x;
  const int z = blockIdx.x;
  const float* cvS = cvg + (size_t)z * 65536;

  const int j   = t & 255;
  const int c   = t >> 8;
  const int jo  = 255 - j;
  const int nbj = (j >> 2) + 1;
  const int bkd = nbj < 32 ? nbj : 32;
  const int nd  = (bkd > c) ? ((bkd - c + 3) >> 2) : 0;       // direct quads
  const int ov  = ((jo >> 2) + 1) - 32;                       // overflow quads in row jo
  const int no  = (ov > c) ? ((ov - c + 3) >> 2) : 0;         // this thread's share
  const int nv  = nd + no;                                    // valid slots (<= 9)
  const int rsR = S_of(j);
  const int rsO = S_of(jo);
  const int coovf = 128 + 4*c - 16*nd;   // overflow col offset = coovf + 16*r

  if (t >= 512 && t < 768) eu[t - 512] = 1.f;
  if (t == 768) eu[256] = 1.f;
  if (t >= 896 && t < 900) redbufU[t - 896] = 64.f;   // S_eu partials at it=0 (eu==1)

  // ---- single pass: global -> registers, masked slice max ----
  float4 eR[9];
  {
    float mx = 0.f;
    #pragma unroll
    for (int r = 0; r < 9; ++r) {
      const bool isd  = r < nd;
      const bool valq = r < nv;
      const int co  = isd ? (4*c + 16*r) : ((coovf + 16*r) & 255);
      const int row = isd ? j : jo;
      float4 v = make_float4(0.f, 0.f, 0.f, 0.f);
      if (valq) {
        v = *(const float4*)&cvS[row*256 + co];
        if (co     <= row) mx = fmaxf(mx, v.x);
        if (co + 1 <= row) mx = fmaxf(mx, v.y);
        if (co + 2 <= row) mx = fmaxf(mx, v.z);
        if (co + 3 <= row) mx = fmaxf(mx, v.w);
      }
      eR[r] = v;                              // raw cv for now
    }
    #pragma unroll
    for (int mm = 32; mm; mm >>= 1) mx = fmaxf(mx, __shfl_xor(mx, mm, 64));
    if ((t & 63) == 0) redbufM[t >> 6] = mx;
  }
  __syncthreads();
  if (t == 0) {
    float m2 = redbufM[0];
    #pragma unroll
    for (int q = 1; q < 16; ++q) m2 = fmaxf(m2, redbufM[q]);
    Msh = m2;
  }
  __syncthreads();
  const float M = Msh;
  const float enM = __expf(-M);

  // ---- exp in registers; write packed triangle to LDS for colsum ----
  #pragma unroll
  for (int r = 0; r < 9; ++r) {
    const bool isd  = r < nd;
    const bool valq = r < nv;
    const int co  = isd ? (4*c + 16*r) : ((coovf + 16*r) & 255);
    const int row = isd ? j : jo;
    const int rs  = isd ? rsR : rsO;
    float4 v = eR[r];
    float4 e;
    e.x = (valq && co     <= row) ? __expf(v.x - M) : 0.f;
    e.y = (valq && co + 1 <= row) ? __expf(v.y - M) : 0.f;
    e.z = (valq && co + 2 <= row) ? __expf(v.z - M) : 0.f;
    e.w = (valq && co + 3 <= row) ? __expf(v.w - M) : 0.f;
    eR[r] = e;
    if (valq) *(float4*)&pE[rs + co] = e;
  }
  __syncthreads();

  const int wv   = __builtin_amdgcn_readfirstlane(t >> 6);  // wave id (scalar)
  const int lane = t & 63;
  const int c0A  = 4 * lane;

  for (int it = 0; it < 8; ++it) {
    // ---- phase A: colsum partials, 16 waves (rows i ≡ wv mod 16) ----
    {
      float4 a = make_float4(0.f, 0.f, 0.f, 0.f);
      #pragma unroll 4
      for (int mq = 0; mq < 16; ++mq) {
        const int i = 16*mq + wv;               // scalar
        const int rs = S_of(i);                 // scalar (SALU)
        const float u = eu[i];                  // uniform broadcast
        if (lane <= (i >> 2)) {
          float4 e = *(const float4*)&pE[rs + c0A];
          a.x = fmaf(e.x, u, a.x); a.y = fmaf(e.y, u, a.y);
          a.z = fmaf(e.z, u, a.z); a.w = fmaf(e.w, u, a.w);
        }
      }
      if (wv < 8) *(float4*)&buf[wv][c0A] = a;
      __syncthreads();
      if (wv >= 8) {
        float4 p = *(const float4*)&buf[wv - 8][c0A];
        p.x += a.x; p.y += a.y; p.z += a.z; p.w += a.w;
        *(float4*)&buf[wv - 8][c0A] = p;
      }
    }
    __syncthreads();
    // ---- phase B: ev from column sums; reduce S_ev; pad ev[256] ----
    if (t < 256) {
      float cj = ((buf[0][t] + buf[1][t]) + (buf[2][t] + buf[3][t]))
               + ((buf[4][t] + buf[5][t]) + (buf[6][t] + buf[7][t]))
               + enM * eu[256];
      float evt = NU_C / cj;
      ev[t] = evt;
      float s = evt;
      #pragma unroll
      for (int mm = 32; mm; mm >>= 1) s += __shfl_xor(s, mm, 64);
      if ((t & 63) == 0) redbufV[t >> 6] = s;
    } else if (t == 960) {
      float S = ((redbufU[0] + redbufU[1]) + (redbufU[2] + redbufU[3])) + eu[256];
      ev[256] = 0.5f / (enM * S);
    }
    __syncthreads();
    // ---- phase C: rowsum partials from registers (all 16 waves) ----
    {
      float d0=0.f,d1=0.f,d2=0.f,d3=0.f;
      float o0=0.f,o1=0.f,o2=0.f,o3=0.f;
      #pragma unroll
      for (int r = 0; r < 9; ++r) {
        const int co = (r < nd) ? (4*c + 16*r) : ((coovf + 16*r) & 255);
        float4 ev4 = *(const float4*)&ev[co];
        float4 e = eR[r];
        float p0 = e.x*ev4.x, p1 = e.y*ev4.y, p2 = e.z*ev4.z, p3 = e.w*ev4.w;
        if (r < nd) { d0 += p0; d1 += p1; d2 += p2; d3 += p3; }
        else        { o0 += p0; o1 += p1; o2 += p2; o3 += p3; }
      }
      buf[c][j]      = (d0 + d1) + (d2 + d3);
      buf[4 + c][jo] = (o0 + o1) + (o2 + o3);
    }
    __syncthreads();
    // ---- phase D: eu from row sums; S_eu reduce; pad eu[256] ----
    if (t < 256) {
      float ri = (((buf[0][t] + buf[1][t]) + (buf[2][t] + buf[3][t]))
                + ((buf[4][t] + buf[5][t]) + (buf[6][t] + buf[7][t])))
               + enM * ev[256];
      float u_ = MU_C / ri;
      eu[t] = u_;
      float s = u_;
      #pragma unroll
      for (int mm = 32; mm; mm >>= 1) s += __shfl_xor(s, mm, 64);
      if ((t & 63) == 0) redbufU[t >> 6] = s;
    } else if (t == 960) {
      float S = ((redbufV[0] + redbufV[1]) + (redbufV[2] + redbufV[3])) + ev[256];
      eu[256] = 0.5f / (enM * S);
    }
    __syncthreads();
  }

  // ---- epilogue: occ / first-max argmax / conf / corr (from registers) ----
  {
    float d0=0.f,d1=0.f,d2=0.f,d3=0.f;
    float o0=0.f,o1=0.f,o2=0.f,o3=0.f;
    float vmd = -1.f, vmo = -1.f;
    int jmd = 1 << 30, jmo = 1 << 30;
    #pragma unroll
    for (int r = 0; r < 9; ++r) {
      const bool isd = r < nd;
      const int co = isd ? (4*c + 16*r) : ((coovf + 16*r) & 255);
      float4 ev4 = *(const float4*)&ev[co];
      float4 e = eR[r];
      float p0 = e.x*ev4.x, p1 = e.y*ev4.y, p2 = e.z*ev4.z, p3 = e.w*ev4.w;
      if (isd) {
        d0 += p0; d1 += p1; d2 += p2; d3 += p3;
        if (p0 > vmd) { vmd = p0; jmd = co;     }
        if (p1 > vmd) { vmd = p1; jmd = co + 1; }
        if (p2 > vmd) { vmd = p2; jmd = co + 2; }
        if (p3 > vmd) { vmd = p3; jmd = co + 3; }
      } else {
        o0 += p0; o1 += p1; o2 += p2; o3 += p3;
        if (p0 > vmo) { vmo = p0; jmo = co;     }
        if (p1 > vmo) { vmo = p1; jmo = co + 1; }
        if (p2 > vmo) { vmo = p2; jmo = co + 2; }
        if (p3 > vmo) { vmo = p3; jmo = co + 3; }
      }
    }
    buf[c][j]      = (d0 + d1) + (d2 + d3);    // phase A': occ partials
    buf[4 + c][jo] = (o0 + o1) + (o2 + o3);
    __syncthreads();
    if (t < 256) {
      float occT = (((buf[0][t] + buf[1][t]) + (buf[2][t] + buf[3][t]))
                  + ((buf[4][t] + buf[5][t]) + (buf[6][t] + buf[7][t])));
      out[OCC_OFF + z*256 + t] = occT * eu[t] * 512.f;
    }
    __syncthreads();
    buf[c][j]      = vmd;                      // phase B': vmax partials
    buf[4 + c][jo] = vmo;
    __syncthreads();
    if (t < 256)
      vbS[t] = fmaxf(fmaxf(fmaxf(buf[0][t], buf[1][t]), fmaxf(buf[2][t], buf[3][t])),
                     fmaxf(fmaxf(buf[4][t], buf[5][t]), fmaxf(buf[6][t], buf[7][t])));
    __syncthreads();
    ((int*)buf)[c*256 + j]        = (vmd == vbS[j])  ? jmd : (1 << 30);  // phase C'
    ((int*)buf)[(4 + c)*256 + jo] = (vmo == vbS[jo]) ? jmo : (1 << 30);
    __syncthreads();
    if (t < 256) {
      const int* bi = (const int*)buf;
      int jb = min(min(min(bi[t], bi[256 + t]), min(bi[512 + t], bi[768 + t])),
                   min(min(bi[1024 + t], bi[1280 + t]), min(bi[1536 + t], bi[1792 + t])));
      const int rsT = S_of(t);
      const float sc = eu[t] * 512.f;
      float conf = 0.f, corr = 0.f;
      #pragma unroll
      for (int d = 0; d < 5; ++d) {
        int jp = jb + d - 2;
        float wgt = 0.f;
        if (jp >= 0 && jp <= t) wgt = pE[rsT + jp] * ev[jp] * sc;
        conf += wgt;
        corr = fmaf(wgt, (float)jp, corr);
      }
      corr = (corr + 1e-4f) / (conf + 1e-4f);
      out[DISP_OFF + z*256 + t] = (float)t - corr;
      out[CONF_OFF + z*256 + t] = conf;
    }
  }
}

extern "C" void kernel_launch(void* const* d_in, const int* in_sizes, int n_in,
                              void* d_out, int out_size, void* d_ws, size_t ws_size,
                              hipStream_t stream) {
  (void)in_sizes; (void)n_in; (void)out_size; (void)ws_size;
  const float* feat = (const float*)d_in[0];
  const float* lnw  = (const float*)d_in[1];
  const float* lnb  = (const float*)d_in[2];
  float* out = (float*)d_out;
  float* stats = (float*)d_ws;          // 2 * 163840 floats = 1.31 MB

  (void)hipFuncSetAttribute((const void*)cv_fused_kernel,
                            hipFuncAttributeMaxDynamicSharedMemorySize, 40960);
  (void)hipFuncSetAttribute((const void*)sink_kernel,
                            hipFuncAttributeMaxDynamicSharedMemorySize, TRI2_TOT*4);

  ln_stats_kernel<<<dim3(2*8*HH), 256, 0, stream>>>(feat, stats);
  cv_fused_kernel<<<dim3(4*NSL + 160), 256, 40960, stream>>>(
      feat, stats, lnw, lnb, out + CV_OFF, out + CVD_OFF);
  sink_kernel<<<dim3(NSL), 1024, TRI2_TOT*4, stream>>>(out + CV_OFF, out);
}

// Round 8
// 275.047 us; speedup vs baseline: 1.0447x; 1.0447x over previous
//
#include <hip/hip_runtime.h>

#define CC 128
#define HH 80
#define WW 256
#define NSL 320                 // 4*80 slices
#define TRI2_TOT 36864          // quad-uniform staggered triangle, floats (144 KB)
#define DISP_OFF 0
#define CONF_OFF 81920
#define OCC_OFF  163840
#define CV_OFF   245760
#define CVD_OFF  21217280
#define NU_C (1.0f/512.0f)
#define MU_C (1.0f/512.0f)
#define ST_N 163840             // 8*80*256 pixels (mean at [0], rstd at [ST_N])
#define LDSW 40                 // ushorts per LDS row (32 data + 8 pad = 80 B)

typedef _Float16 f16;
typedef f16 f16x8 __attribute__((ext_vector_type(8)));
typedef float f32x4 __attribute__((ext_vector_type(4)));

// Quad m (rows 4m..4m+3) all have padded length ell(m) = 4 + 32*((m+7)>>3).
// Row start S(i) = Q(m) + (i&3)*ell(m), Q(m) = 16m + 128*G(m).
__device__ __forceinline__ int ell_of(int m) { return 4 + (((m + 7) >> 3) << 5); }
__device__ __forceinline__ int S_of(int i) {
  int m = i >> 2;
  int q = (m + 7) >> 3, r = (m + 7) & 7;
  int Q = 16*m + ((q*(q-1)) << 9) + ((r*q) << 7);
  return Q + (i & 3) * ell_of(m);
}

// ---------------- LN stats: one pass over feature, 1.3 MB out ----------------
__global__ __launch_bounds__(256)
void ln_stats_kernel(const float* __restrict__ feat, float* __restrict__ stats) {
  __shared__ __align__(16) float4 psum[8][32];
  __shared__ __align__(16) float4 psq[8][32];
  const int t = threadIdx.x;
  const int id = blockIdx.x;              // 0..1279 = bh*2 + wx
  const int wx = id & 1, bh = id >> 1;
  const int bb = bh / HH, h = bh % HH;
  const int tw = t & 31, tc = t >> 5;
  const float* p = feat + ((size_t)(bb*CC + tc*16)*HH + h)*WW + wx*128 + tw*4;
  float4 s4  = make_float4(0.f, 0.f, 0.f, 0.f);
  float4 s24 = make_float4(0.f, 0.f, 0.f, 0.f);
  #pragma unroll
  for (int cc = 0; cc < 16; ++cc) {
    float4 v = *(const float4*)(p + (size_t)cc*HH*WW);
    s4.x += v.x; s4.y += v.y; s4.z += v.z; s4.w += v.w;
    s24.x = fmaf(v.x, v.x, s24.x); s24.y = fmaf(v.y, v.y, s24.y);
    s24.z = fmaf(v.z, v.z, s24.z); s24.w = fmaf(v.w, v.w, s24.w);
  }
  psum[tc][tw] = s4; psq[tc][tw] = s24;
  __syncthreads();
  if (t < 32) {
    float4 S  = psum[0][t];
    float4 S2 = psq[0][t];
    #pragma unroll
    for (int k = 1; k < 8; ++k) {
      float4 a = psum[k][t], b = psq[k][t];
      S.x += a.x; S.y += a.y; S.z += a.z; S.w += a.w;
      S2.x += b.x; S2.y += b.y; S2.z += b.z; S2.w += b.w;
    }
    float4 mu = make_float4(S.x*(1.f/CC), S.y*(1.f/CC), S.z*(1.f/CC), S.w*(1.f/CC));
    float4 rs;
    rs.x = rsqrtf(fmaf(-mu.x, mu.x, S2.x*(1.f/CC)) + 1e-5f);
    rs.y = rsqrtf(fmaf(-mu.y, mu.y, S2.y*(1.f/CC)) + 1e-5f);
    rs.z = rsqrtf(fmaf(-mu.z, mu.z, S2.z*(1.f/CC)) + 1e-5f);
    rs.w = rsqrtf(fmaf(-mu.w, mu.w, S2.w*(1.f/CC)) + 1e-5f);
    *(float4*)&stats[(size_t)bh*WW + wx*128 + 4*t]        = mu;
    *(float4*)&stats[ST_N + (size_t)bh*WW + wx*128 + 4*t] = rs;
  }
}

// ------------- fused cost-volume GEMM (cv + cvd), MFMA fp16-split ------------
// (validated R6: absmax 3.0, cv_fused < 99 us)
__global__ __launch_bounds__(256, 3)
void cv_fused_kernel(const float* __restrict__ feat, const float* __restrict__ stats,
                     const float* __restrict__ lnw, const float* __restrict__ lnb,
                     float* __restrict__ cv_out, float* __restrict__ cvd_out) {
  extern __shared__ unsigned short smu[];       // 20480 ushorts = 40960 B
  unsigned short* Ah = smu;
  unsigned short* Al = smu + 5120;
  unsigned short* Bh = smu + 10240;
  unsigned short* Bl = smu + 15360;
  __shared__ __align__(16) float rmean[256];
  __shared__ __align__(16) float rrstd[256];
  __shared__ float lwS[128], lbS[128];
  const int t = threadIdx.x;
  const int P = blockIdx.x;
  if (t < 128) { lwS[t] = lnw[t]; lbS[t] = lnb[t]; }
  const int l = t & 63, w = t >> 6;             // lane, wave
  const int wm = w >> 1, wn = w & 1;            // wave tile (64x64)
  const int fr = l & 15, fg = l >> 4;           // frag row, k-group
  const int row = t & 127, khalf = t >> 7;      // staging coords

  const bool iscv = (P < 4*NSL);
  int zz = 0, i0 = 0, j0 = 0, id = 0, ws = 1;
  size_t baseA, baseB;
  if (iscv) {
    const int x = P & 7, m = P >> 3;
    const int q = m & 3, zhi = m >> 2;
    zz = zhi*8 + x;                             // 0..319
    i0 = (q >> 1) * 128; j0 = (q & 1) * 128;
    const int b = zz / HH, h = zz % HH;
    baseA = ((size_t)b*CC*HH + (size_t)h)*WW + i0;
    baseB = ((size_t)(b+4)*CC*HH + (size_t)h)*WW + j0;
    const int isA = (t < 128);
    const int rr_ = isA ? (i0 + t) : (j0 + (t - 128));
    const int bb  = isA ? b : (b + 4);
    const size_t si = ((size_t)bb*HH + h)*WW + rr_;
    rmean[t] = stats[si];
    rrstd[t] = stats[ST_N + si];
  } else {
    id = P - 4*NSL;                             // 0..159
    const int b = id / 40, hd = id % 40, h = 2*hd;
    ws = 2;
    baseA = ((size_t)b*CC*HH + (size_t)h)*WW;
    baseB = ((size_t)(b+4)*CC*HH + (size_t)h)*WW;
    const int isA = (t < 128);
    const int rowd = isA ? t : (t - 128);
    const int bb = isA ? b : (b + 4);
    const size_t si = ((size_t)bb*HH + h)*WW + 2*rowd;
    rmean[t] = stats[si];
    rrstd[t] = stats[ST_N + si];
  }

  f32x4 acc[4][4];
  #pragma unroll
  for (int mi = 0; mi < 4; ++mi)
    #pragma unroll
    for (int ni = 0; ni < 4; ++ni)
      acc[mi][ni] = (f32x4){0.f, 0.f, 0.f, 0.f};

  float qa[16], qb[16];
  auto loadC = [&](int kc) {
    const size_t co = (size_t)(kc*32 + khalf*16)*HH*WW + (size_t)(row*ws);
    #pragma unroll
    for (int e = 0; e < 16; ++e) {
      qa[e] = feat[baseA + co + (size_t)e*HH*WW];
      qb[e] = feat[baseB + co + (size_t)e*HH*WW];
    }
  };
  auto storeC = [&](int kc) {
    const float rmA = rmean[row],     rrA = rrstd[row];
    const float rmB = rmean[128+row], rrB = rrstd[128+row];
    f16x8 vah[2], val[2], vbh[2], vbl[2];
    #pragma unroll
    for (int e = 0; e < 16; ++e) {
      const int ch = kc*32 + khalf*16 + e;
      const float lw = lwS[ch], lb = lbS[ch];
      float va = (qa[e] - rmA) * rrA * lw + lb;
      f16 ha = (f16)va;
      vah[e >> 3][e & 7] = ha;
      val[e >> 3][e & 7] = (f16)(va - (float)ha);
      float vb = (qb[e] - rmB) * rrB * lw + lb;
      f16 hb = (f16)vb;
      vbh[e >> 3][e & 7] = hb;
      vbl[e >> 3][e & 7] = (f16)(vb - (float)hb);
    }
    const int off = row*LDSW + khalf*16;
    *(f16x8*)&Ah[off] = vah[0]; *(f16x8*)&Ah[off + 8] = vah[1];
    *(f16x8*)&Al[off] = val[0]; *(f16x8*)&Al[off + 8] = val[1];
    *(f16x8*)&Bh[off] = vbh[0]; *(f16x8*)&Bh[off + 8] = vbh[1];
    *(f16x8*)&Bl[off] = vbl[0]; *(f16x8*)&Bl[off + 8] = vbl[1];
  };
  auto compute = [&]() {
    f16x8 a_h[4], a_l[4];
    #pragma unroll
    for (int mi = 0; mi < 4; ++mi) {
      const int r0 = (wm*64 + mi*16 + fr)*LDSW + fg*8;
      a_h[mi] = *(const f16x8*)&Ah[r0];
      a_l[mi] = *(const f16x8*)&Al[r0];
    }
    #pragma unroll
    for (int ni = 0; ni < 4; ++ni) {
      const int c0 = (wn*64 + ni*16 + fr)*LDSW + fg*8;
      f16x8 b_h = *(const f16x8*)&Bh[c0];
      f16x8 b_l = *(const f16x8*)&Bl[c0];
      #pragma unroll
      for (int mi = 0; mi < 4; ++mi) {
        acc[mi][ni] = __builtin_amdgcn_mfma_f32_16x16x32_f16(a_h[mi], b_h, acc[mi][ni], 0, 0, 0);
        acc[mi][ni] = __builtin_amdgcn_mfma_f32_16x16x32_f16(a_h[mi], b_l, acc[mi][ni], 0, 0, 0);
        acc[mi][ni] = __builtin_amdgcn_mfma_f32_16x16x32_f16(a_l[mi], b_h, acc[mi][ni], 0, 0, 0);
      }
    }
  };

  loadC(0);
  __syncthreads();                 // rmean/lwS visible
  storeC(0);
  for (int kc = 0; kc < 4; ++kc) {
    __syncthreads();               // LDS tile ready
    if (kc < 3) loadC(kc + 1);     // prefetch next chunk under compute
    compute();
    __syncthreads();               // all reads done before overwrite
    if (kc < 3) storeC(kc + 1);
  }

  // ---- epilogue: C/D layout row=(l>>4)*4+reg, col=l&15 ----
  if (iscv) {
    #pragma unroll
    for (int mi = 0; mi < 4; ++mi)
      #pragma unroll
      for (int ni = 0; ni < 4; ++ni) {
        f32x4 v = acc[mi][ni];
        const int orow = i0 + wm*64 + mi*16 + fg*4;
        const int ocol = j0 + wn*64 + ni*16 + fr;
        size_t ob = ((size_t)zz*256 + orow)*256 + ocol;
        cv_out[ob]       = v[0];
        cv_out[ob + 256] = v[1];
        cv_out[ob + 512] = v[2];
        cv_out[ob + 768] = v[3];
      }
  } else {
    #pragma unroll
    for (int mi = 0; mi < 4; ++mi)
      #pragma unroll
      for (int ni = 0; ni < 4; ++ni) {
        f32x4 v = acc[mi][ni];
        const int orow = wm*64 + mi*16 + fg*4;
        const int ocol = wn*64 + ni*16 + fr;
        size_t ob = ((size_t)id*128 + orow)*128 + ocol;
        cvd_out[ob]       = v[0];
        cvd_out[ob + 128] = v[1];
        cvd_out[ob + 256] = v[2];
        cvd_out[ob + 384] = v[3];
      }
  }
}

// ---------------- Sinkhorn: row AND column register caches -------------------
// eR[9]: row stripes (R6, unchanged) feed rowsum/epilogue. NEW eC[9]: column
// stripes feed colsum -- phase A's per-iteration 133 KB LDS triangle stream
// (R6/R7 bottleneck: 8.98M intrinsic b128 conflict cycles, LDS-bound) is
// DELETED. Column pairing: thread (j<128,c) owns col j quads ib in [32,63],
// ib≡c(4) (exactly 8); thread (j>=128,c) owns col j's own quads + partner
// col (255-j)'s low quads ib in [63-(j>>2),31] -- <=9 total. eC recomputed
// as expf(cvS[i*256+j]-M): same formula/inputs as pE -> bitwise-identical
// elements; only colsum add order changes (same class as R1/R6 reorders).
// S_eu reduce lives in phase D (R7 placement, correctness-verified).
__global__ __launch_bounds__(1024)
__attribute__((amdgpu_waves_per_eu(4, 4)))
void sink_kernel(const float* __restrict__ cvg, float* __restrict__ out) {
  extern __shared__ float pE[];                 // TRI2_TOT floats
  __shared__ __align__(16) float eu[260];
  __shared__ __align__(16) float ev[260];
  __shared__ __align__(16) float buf[8][256];
  __shared__ float vbS[256];
  __shared__ float redbufU[4], redbufV[4], redbufM[16];
  __shared__ float Msh;
  const int t = threadIdx.x;
  const int z = blockIdx.x;
  const float* cvS = cvg + (size_t)z * 65536;

  const int j   = t & 255;
  const int c   = t >> 8;
  const int jo  = 255 - j;
  const int nbj = (j >> 2) + 1;
  const int bkd = nbj < 32 ? nbj : 32;
  const int nd  = (bkd > c) ? ((bkd - c + 3) >> 2) : 0;       // direct quads (rows)
  const int ov  = ((jo >> 2) + 1) - 32;                       // overflow quads in row jo
  const int no  = (ov > c) ? ((ov - c + 3) >> 2) : 0;         // this thread's share
  const int nv  = nd + no;                                    // valid row slots (<= 9)
  const int rsR = S_of(j);
  const int rsO = S_of(jo);
  const int coovf = 128 + 4*c - 16*nd;   // overflow col offset = coovf + 16*r

  // column-cache geometry
  const int mj = j >> 2;
  int ib0_1, n1, ib0_2, n2;
  if (j < 128) {
    ib0_1 = 32 + c; n1 = 8;
    ib0_2 = 64; n2 = 0;                       // no partner work
  } else {
    ib0_1 = mj + ((c - mj) & 3);
    n1 = (ib0_1 <= 63) ? (((63 - ib0_1) >> 2) + 1) : 0;
    const int mo = 63 - mj;                   // partner col (jo<128) first quad
    ib0_2 = mo + ((c - mo) & 3);
    n2 = (ib0_2 <= 31) ? (((31 - ib0_2) >> 2) + 1) : 0;
  }

  if (t >= 512 && t < 768) eu[t - 512] = 1.f;
  if (t == 768) eu[256] = 1.f;
  if (t >= 896 && t < 900) redbufU[t - 896] = 64.f;   // S_eu partials at it=0 (eu==1)

  // ---- single pass: global -> registers, masked slice max ----
  float4 eR[9];
  {
    float mx = 0.f;
    #pragma unroll
    for (int r = 0; r < 9; ++r) {
      const bool isd  = r < nd;
      const bool valq = r < nv;
      const int co  = isd ? (4*c + 16*r) : ((coovf + 16*r) & 255);
      const int row = isd ? j : jo;
      float4 v = make_float4(0.f, 0.f, 0.f, 0.f);
      if (valq) {
        v = *(const float4*)&cvS[row*256 + co];
        if (co     <= row) mx = fmaxf(mx, v.x);
        if (co + 1 <= row) mx = fmaxf(mx, v.y);
        if (co + 2 <= row) mx = fmaxf(mx, v.z);
        if (co + 3 <= row) mx = fmaxf(mx, v.w);
      }
      eR[r] = v;                              // raw cv for now
    }
    #pragma unroll
    for (int mm = 32; mm; mm >>= 1) mx = fmaxf(mx, __shfl_xor(mx, mm, 64));
    if ((t & 63) == 0) redbufM[t >> 6] = mx;
  }
  __syncthreads();
  if (t == 0) {
    float m2 = redbufM[0];
    #pragma unroll
    for (int q = 1; q < 16; ++q) m2 = fmaxf(m2, redbufM[q]);
    Msh = m2;
  }
  __syncthreads();
  const float M = Msh;
  const float enM = __expf(-M);

  // ---- exp in registers; write packed triangle to LDS (epilogue use) ----
  #pragma unroll
  for (int r = 0; r < 9; ++r) {
    const bool isd  = r < nd;
    const bool valq = r < nv;
    const int co  = isd ? (4*c + 16*r) : ((coovf + 16*r) & 255);
    const int row = isd ? j : jo;
    const int rs  = isd ? rsR : rsO;
    float4 v = eR[r];
    float4 e;
    e.x = (valq && co     <= row) ? __expf(v.x - M) : 0.f;
    e.y = (valq && co + 1 <= row) ? __expf(v.y - M) : 0.f;
    e.z = (valq && co + 2 <= row) ? __expf(v.z - M) : 0.f;
    e.w = (valq && co + 3 <= row) ? __expf(v.w - M) : 0.f;
    eR[r] = e;
    if (valq) *(float4*)&pE[rs + co] = e;
  }

  // ---- build column cache eC from global (same formula -> identical bits) --
  float4 eC[9];
  #pragma unroll
  for (int r = 0; r < 9; ++r) {
    const bool own  = r < n1;
    const int  rr2  = r - n1;
    const bool valq = own || (rr2 < n2);
    const int  ib   = own ? (ib0_1 + 4*r) : (ib0_2 + 4*rr2);
    const int  colq = own ? j : jo;
    float4 e = make_float4(0.f, 0.f, 0.f, 0.f);
    if (valq) {
      const int ibase = 4 * (ib & 63);
      if (colq <= ibase    ) e.x = __expf(cvS[(ibase    )*256 + colq] - M);
      if (colq <= ibase + 1) e.y = __expf(cvS[(ibase + 1)*256 + colq] - M);
      if (colq <= ibase + 2) e.z = __expf(cvS[(ibase + 2)*256 + colq] - M);
      if (colq <= ibase + 3) e.w = __expf(cvS[(ibase + 3)*256 + colq] - M);
    }
    eC[r] = e;
  }
  __syncthreads();

  for (int it = 0; it < 8; ++it) {
    // ---- phase A': colsum partials from eC registers (all 16 waves) ----
    {
      float o0=0.f,o1=0.f,o2=0.f,o3=0.f;     // own column j
      float p0=0.f,p1=0.f,p2=0.f,p3=0.f;     // partner column jo
      #pragma unroll
      for (int r = 0; r < 9; ++r) {
        const bool own  = r < n1;
        const int  rr2  = r - n1;
        const bool valq = own || (rr2 < n2);
        const int  ib   = own ? (ib0_1 + 4*r) : (ib0_2 + 4*rr2);
        if (valq) {
          float4 u4 = *(const float4*)&eu[4 * (ib & 63)];
          float4 e = eC[r];
          if (own) {
            o0 = fmaf(e.x, u4.x, o0); o1 = fmaf(e.y, u4.y, o1);
            o2 = fmaf(e.z, u4.z, o2); o3 = fmaf(e.w, u4.w, o3);
          } else {
            p0 = fmaf(e.x, u4.x, p0); p1 = fmaf(e.y, u4.y, p1);
            p2 = fmaf(e.z, u4.z, p2); p3 = fmaf(e.w, u4.w, p3);
          }
        }
      }
      buf[c][j]      = (o0 + o1) + (o2 + o3);
      buf[4 + c][jo] = (p0 + p1) + (p2 + p3);
    }
    __syncthreads();
    // ---- phase B: ev from column sums; reduce S_ev; pad ev[256] ----
    if (t < 256) {
      float cj = ((buf[0][t] + buf[1][t]) + (buf[2][t] + buf[3][t]))
               + ((buf[4][t] + buf[5][t]) + (buf[6][t] + buf[7][t]))
               + enM * eu[256];
      float evt = NU_C / cj;
      ev[t] = evt;
      float s = evt;
      #pragma unroll
      for (int mm = 32; mm; mm >>= 1) s += __shfl_xor(s, mm, 64);
      if ((t & 63) == 0) redbufV[t >> 6] = s;
    } else if (t == 960) {
      float S = ((redbufU[0] + redbufU[1]) + (redbufU[2] + redbufU[3])) + eu[256];
      ev[256] = 0.5f / (enM * S);
    }
    __syncthreads();
    // ---- phase C: rowsum partials from eR registers (all 16 waves) ----
    {
      float d0=0.f,d1=0.f,d2=0.f,d3=0.f;
      float o0=0.f,o1=0.f,o2=0.f,o3=0.f;
      #pragma unroll
      for (int r = 0; r < 9; ++r) {
        const int co = (r < nd) ? (4*c + 16*r) : ((coovf + 16*r) & 255);
        float4 ev4 = *(const float4*)&ev[co];
        float4 e = eR[r];
        float p0 = e.x*ev4.x, p1 = e.y*ev4.y, p2 = e.z*ev4.z, p3 = e.w*ev4.w;
        if (r < nd) { d0 += p0; d1 += p1; d2 += p2; d3 += p3; }
        else        { o0 += p0; o1 += p1; o2 += p2; o3 += p3; }
      }
      buf[c][j]      = (d0 + d1) + (d2 + d3);
      buf[4 + c][jo] = (o0 + o1) + (o2 + o3);
    }
    __syncthreads();
    // ---- phase D: eu from row sums; S_eu reduce; pad eu[256] ----
    if (t < 256) {
      float ri = (((buf[0][t] + buf[1][t]) + (buf[2][t] + buf[3][t]))
                + ((buf[4][t] + buf[5][t]) + (buf[6][t] + buf[7][t])))
               + enM * ev[256];
      float u_ = MU_C / ri;
      eu[t] = u_;
      float s = u_;
      #pragma unroll
      for (int mm = 32; mm; mm >>= 1) s += __shfl_xor(s, mm, 64);
      if ((t & 63) == 0) redbufU[t >> 6] = s;
    } else if (t == 960) {
      float S = ((redbufV[0] + redbufV[1]) + (redbufV[2] + redbufV[3])) + ev[256];
      eu[256] = 0.5f / (enM * S);
    }
    __syncthreads();
  }

  // ---- epilogue: occ / first-max argmax / conf / corr (from registers) ----
  {
    float d0=0.f,d1=0.f,d2=0.f,d3=0.f;
    float o0=0.f,o1=0.f,o2=0.f,o3=0.f;
    float vmd = -1.f, vmo = -1.f;
    int jmd = 1 << 30, jmo = 1 << 30;
    #pragma unroll
    for (int r = 0; r < 9; ++r) {
      const bool isd = r < nd;
      const int co = isd ? (4*c + 16*r) : ((coovf + 16*r) & 255);
      float4 ev4 = *(const float4*)&ev[co];
      float4 e = eR[r];
      float p0 = e.x*ev4.x, p1 = e.y*ev4.y, p2 = e.z*ev4.z, p3 = e.w*ev4.w;
      if (isd) {
        d0 += p0; d1 += p1; d2 += p2; d3 += p3;
        if (p0 > vmd) { vmd = p0; jmd = co;     }
        if (p1 > vmd) { vmd = p1; jmd = co + 1; }
        if (p2 > vmd) { vmd = p2; jmd = co + 2; }
        if (p3 > vmd) { vmd = p3; jmd = co + 3; }
      } else {
        o0 += p0; o1 += p1; o2 += p2; o3 += p3;
        if (p0 > vmo) { vmo = p0; jmo = co;     }
        if (p1 > vmo) { vmo = p1; jmo = co + 1; }
        if (p2 > vmo) { vmo = p2; jmo = co + 2; }
        if (p3 > vmo) { vmo = p3; jmo = co + 3; }
      }
    }
    buf[c][j]      = (d0 + d1) + (d2 + d3);    // phase A': occ partials
    buf[4 + c][jo] = (o0 + o1) + (o2 + o3);
    __syncthreads();
    if (t < 256) {
      float occT = (((buf[0][t] + buf[1][t]) + (buf[2][t] + buf[3][t]))
                  + ((buf[4][t] + buf[5][t]) + (buf[6][t] + buf[7][t])));
      out[OCC_OFF + z*256 + t] = occT * eu[t] * 512.f;
    }
    __syncthreads();
    buf[c][j]      = vmd;                      // phase B': vmax partials
    buf[4 + c][jo] = vmo;
    __syncthreads();
    if (t < 256)
      vbS[t] = fmaxf(fmaxf(fmaxf(buf[0][t], buf[1][t]), fmaxf(buf[2][t], buf[3][t])),
                     fmaxf(fmaxf(buf[4][t], buf[5][t]), fmaxf(buf[6][t], buf[7][t])));
    __syncthreads();
    ((int*)buf)[c*256 + j]        = (vmd == vbS[j])  ? jmd : (1 << 30);  // phase C'
    ((int*)buf)[(4 + c)*256 + jo] = (vmo == vbS[jo]) ? jmo : (1 << 30);
    __syncthreads();
    if (t < 256) {
      const int* bi = (const int*)buf;
      int jb = min(min(min(bi[t], bi[256 + t]), min(bi[512 + t], bi[768 + t])),
                   min(min(bi[1024 + t], bi[1280 + t]), min(bi[1536 + t], bi[1792 + t])));
      const int rsT = S_of(t);
      const float sc = eu[t] * 512.f;
      float conf = 0.f, corr = 0.f;
      #pragma unroll
      for (int d = 0; d < 5; ++d) {
        int jp = jb + d - 2;
        float wgt = 0.f;
        if (jp >= 0 && jp <= t) wgt = pE[rsT + jp] * ev[jp] * sc;
        conf += wgt;
        corr = fmaf(wgt, (float)jp, corr);
      }
      corr = (corr + 1e-4f) / (conf + 1e-4f);
      out[DISP_OFF + z*256 + t] = (float)t - corr;
      out[CONF_OFF + z*256 + t] = conf;
    }
  }
}

extern "C" void kernel_launch(void* const* d_in, const int* in_sizes, int n_in,
                              void* d_out, int out_size, void* d_ws, size_t ws_size,
                              hipStream_t stream) {
  (void)in_sizes; (void)n_in; (void)out_size; (void)ws_size;
  const float* feat = (const float*)d_in[0];
  const float* lnw  = (const float*)d_in[1];
  const float* lnb  = (const float*)d_in[2];
  float* out = (float*)d_out;
  float* stats = (float*)d_ws;          // 2 * 163840 floats = 1.31 MB

  (void)hipFuncSetAttribute((const void*)cv_fused_kernel,
                            hipFuncAttributeMaxDynamicSharedMemorySize, 40960);
  (void)hipFuncSetAttribute((const void*)sink_kernel,
                            hipFuncAttributeMaxDynamicSharedMemorySize, TRI2_TOT*4);

  ln_stats_kernel<<<dim3(2*8*HH), 256, 0, stream>>>(feat, stats);
  cv_fused_kernel<<<dim3(4*NSL + 160), 256, 40960, stream>>>(
      feat, stats, lnw, lnb, out + CV_OFF, out + CVD_OFF);
  sink_kernel<<<dim3(NSL), 1024, TRI2_TOT*4, stream>>>(out + CV_OFF, out);
}